// Round 9
// baseline (605.873 us; speedup 1.0000x reference)
//
#include <hip/hip_runtime.h>

#define T_DIM 128
#define B_DIM 2048
#define D_DIM 1024
#define KW 8
#define NCOL (B_DIM * 16)      // 32768 columns

// Per double-buffer half: A-tile 32KB [kc<4][jh<2][mloc<256][16B]
//                       + X-tile 32KB [kc<4][jh<2][col<256][16B]
#define BUFB 65536

typedef _Float16 f16x8 __attribute__((ext_vector_type(8)));
typedef float    f32x16 __attribute__((ext_vector_type(16)));

static __device__ __forceinline__ int imax(int a, int b) { return a > b ? a : b; }
static __device__ __forceinline__ int imin(int a, int b) { return a < b ? a : b; }

__device__ __forceinline__ void gload_lds16(const void* g, void* l) {
    __builtin_amdgcn_global_load_lds(
        (const __attribute__((address_space(1))) unsigned int*)g,
        (__attribute__((address_space(3))) unsigned int*)l, 16, 0, 0);
}

__device__ __forceinline__ f16x8 cvt2(float4 u, float4 v) {
    f16x8 h;
    h[0] = (_Float16)u.x; h[1] = (_Float16)u.y;
    h[2] = (_Float16)u.z; h[3] = (_Float16)u.w;
    h[4] = (_Float16)v.x; h[5] = (_Float16)v.y;
    h[6] = (_Float16)v.z; h[7] = (_Float16)v.w;
    return h;
}

// ---------------------------------------------------------------------------
// Kernel 0: W1 fp32 [m][k] -> W1g: 64 slabs (ktile<16 x mt<4) of 32KB, each
// the exact linear LDS image [kc<4][jh<2][mloc<256][8 f16]:
//   element = W1[mt*256 + mloc][ktile*64 + kc*16 + jh*8 + j]
// ---------------------------------------------------------------------------
__global__ void k_cvt_w1(const float* __restrict__ W1, _Float16* __restrict__ W1g) {
    int i  = blockIdx.x * 256 + threadIdx.x;   // 65536 threads
    int m  = i >> 6;
    int r  = i & 63;
    int kt = r >> 2;
    int kc = r & 3;
    const float* src = W1 + (size_t)m * D_DIM + kt * 64 + kc * 16;
    float4 x0 = *(const float4*)(src);
    float4 x1 = *(const float4*)(src + 4);
    float4 x2 = *(const float4*)(src + 8);
    float4 x3 = *(const float4*)(src + 12);
    int slab = kt * 4 + (m >> 8);
    int mloc = m & 255;
    _Float16* dst = W1g + (size_t)slab * 16384 + kc * 4096 + mloc * 8;
    *(f16x8*)(dst)        = cvt2(x0, x1);   // jh = 0
    *(f16x8*)(dst + 2048) = cvt2(x2, x3);   // jh = 1
}

// ---------------------------------------------------------------------------
// Kernel 1 (fused gather + 256x256 GEMM + tanh/W2 epilogue):
// grid = 512 blocks (4 mt x 128 cg, XCD-bijective swizzle so the 4 mt-
// siblings of a cg share one XCD's L2 for the X stream).
// 8 waves (mg<2 x ng<4), wave-tile 128m x 64n, acc[4][2] of 32x32x16.
// K-loop: 16 tiles of BK=64, double-buffered; per iter 4 MFMA phases with
// staging issued in phases 0-1 (X fp32 loads first, then A global_load_lds),
// X cvt+ds_write after phase 3, ONE barrier per iter (all writes -> nxt buf).
// Writes s_part[mt][col] = sum over 256 m of W2[m]*tanh(dot).
// NOTE: __launch_bounds__(512, 2) is load-bearing: without the ",2" the
// compiler budgets ~104 VGPR and spills the 128-reg accumulator (round 8:
// 668 us, MfmaUtil 4%).
// ---------------------------------------------------------------------------
__launch_bounds__(512, 2)
__global__ void k_gemm(const float* __restrict__ hctx,
                       const int*   __restrict__ offsets,
                       const int*   __restrict__ stc,
                       const int*   __restrict__ sep_l,
                       const _Float16* __restrict__ W1g,
                       const float* __restrict__ W2,
                       float* __restrict__ s_part /* [4][NCOL] */) {
    __shared__ __align__(16) char lds[2 * BUFB];

    int orig = blockIdx.x;
    int wgid = (orig & 7) * 64 + (orig >> 3);   // bijective: 512 % 8 == 0
    int mt   = wgid & 3;
    int cg   = wgid >> 2;

    int tid  = threadIdx.x;
    int wid  = tid >> 6;
    int lane = tid & 63;
    int lr   = lane & 31;
    int hi   = lane >> 5;
    int mg   = wid >> 2;      // 0..1
    int ng   = wid & 3;       // 0..3

    // ---- X gather setup: thread owns (col, khalf) ----
    int s_col = tid & 255;
    int khalf = tid >> 8;     // 0..1 (k-half of 32 within BK=64)
    int col = cg * 256 + s_col;
    int b   = col >> 4;
    int li  = col & 15;
    int off = offsets[b];
    int sep = sep_l[b];
    int st  = stc[b];
    bool in1 = (off <= sep);
    int start = in1 ? imax(off - KW, 0)   : imax(off - KW, sep + 1);
    int end   = in1 ? imin(off + KW, sep) : imin(off + KW, st);
    int idx = start + li;
    bool valid = (idx < end);
    int tc = imin(imax(idx, 0), T_DIM - 1);
    const float* hrow = hctx + ((size_t)tc * B_DIM + b) * D_DIM + khalf * 32;
    int xw_base = ((khalf * 2) * 2) * 4096 + s_col * 16;   // + (w*2+jh)*4096

    // ---- A gload geometry ----
    const char* wg = (const char*)W1g;
    int a_dst = wid * 1024;                 // + p*8192 (dest in A region)
    int a_src = wid * 1024 + lane * 16;     // + slab + p*8192

    // ---- frag read offsets ----
    int a_off = (mg * 128 + lr) * 16;       // + (kc*2+hi)*4096 + mf*512
    int x_off = (ng * 64 + lr) * 16;        // + (kc*2+hi)*4096 + nf*512

    f32x16 acc[4][2];
#pragma unroll
    for (int f = 0; f < 4; ++f)
#pragma unroll
        for (int nf = 0; nf < 2; ++nf)
#pragma unroll
            for (int i = 0; i < 16; ++i) acc[f][nf][i] = 0.f;

    float4 z = {0.f, 0.f, 0.f, 0.f};

    // ---- prologue: stage tile 0 into buf0 ----
    {
        size_t sl = (size_t)(0 * 4 + mt) * 32768;
#pragma unroll
        for (int p = 0; p < 4; ++p)
            gload_lds16(wg + sl + p * 8192 + a_src, lds + p * 8192 + a_dst);
        float4 xr[8];
#pragma unroll
        for (int i = 0; i < 8; ++i)
            xr[i] = valid ? *(const float4*)(hrow + i * 4) : z;
#pragma unroll
        for (int w = 0; w < 2; ++w)
#pragma unroll
            for (int jh = 0; jh < 2; ++jh)
                *(f16x8*)(lds + 32768 + xw_base + (w * 2 + jh) * 4096) =
                    cvt2(xr[w * 4 + jh * 2], xr[w * 4 + jh * 2 + 1]);
    }
    __syncthreads();

#define PHASE(kc)                                                              \
    {                                                                          \
        const char* pa = bA + ((kc) * 2 + hi) * 4096;                          \
        const char* px = bX + ((kc) * 2 + hi) * 4096;                          \
        f16x8 af0 = *(const f16x8*)(pa + a_off);                               \
        f16x8 af1 = *(const f16x8*)(pa + a_off + 512);                         \
        f16x8 af2 = *(const f16x8*)(pa + a_off + 1024);                        \
        f16x8 af3 = *(const f16x8*)(pa + a_off + 1536);                        \
        f16x8 xf0 = *(const f16x8*)(px + x_off);                               \
        f16x8 xf1 = *(const f16x8*)(px + x_off + 512);                         \
        __builtin_amdgcn_s_setprio(1);                                         \
        acc[0][0] = __builtin_amdgcn_mfma_f32_32x32x16_f16(af0, xf0, acc[0][0], 0, 0, 0); \
        acc[1][0] = __builtin_amdgcn_mfma_f32_32x32x16_f16(af1, xf0, acc[1][0], 0, 0, 0); \
        acc[2][0] = __builtin_amdgcn_mfma_f32_32x32x16_f16(af2, xf0, acc[2][0], 0, 0, 0); \
        acc[3][0] = __builtin_amdgcn_mfma_f32_32x32x16_f16(af3, xf0, acc[3][0], 0, 0, 0); \
        acc[0][1] = __builtin_amdgcn_mfma_f32_32x32x16_f16(af0, xf1, acc[0][1], 0, 0, 0); \
        acc[1][1] = __builtin_amdgcn_mfma_f32_32x32x16_f16(af1, xf1, acc[1][1], 0, 0, 0); \
        acc[2][1] = __builtin_amdgcn_mfma_f32_32x32x16_f16(af2, xf1, acc[2][1], 0, 0, 0); \
        acc[3][1] = __builtin_amdgcn_mfma_f32_32x32x16_f16(af3, xf1, acc[3][1], 0, 0, 0); \
        __builtin_amdgcn_s_setprio(0);                                         \
    }

    // ---- main loop: 16 K-tiles of 64 ----
    for (int t = 0; t < 16; ++t) {
        const char* bA = lds + (t & 1) * BUFB;
        const char* bX = bA + 32768;
        char* nA = lds + ((t & 1) ^ 1) * BUFB;
        char* nX = nA + 32768;
        bool pre = (t < 15);
        size_t sl = (size_t)((t + 1) * 4 + mt) * 32768;
        const float* xsrc = hrow + (t + 1) * 64;

        float4 xr[8];
        // phase 0: issue X loads 0-3 (first), then A gload rounds 0-1
        if (pre) {
            xr[0] = valid ? *(const float4*)(xsrc)      : z;
            xr[1] = valid ? *(const float4*)(xsrc + 4)  : z;
            xr[2] = valid ? *(const float4*)(xsrc + 8)  : z;
            xr[3] = valid ? *(const float4*)(xsrc + 12) : z;
            gload_lds16(wg + sl + a_src,        nA + a_dst);
            gload_lds16(wg + sl + 8192 + a_src, nA + 8192 + a_dst);
        }
        PHASE(0)
        // phase 1: X loads 4-7, A gload rounds 2-3
        if (pre) {
            xr[4] = valid ? *(const float4*)(xsrc + 16) : z;
            xr[5] = valid ? *(const float4*)(xsrc + 20) : z;
            xr[6] = valid ? *(const float4*)(xsrc + 24) : z;
            xr[7] = valid ? *(const float4*)(xsrc + 28) : z;
            gload_lds16(wg + sl + 16384 + a_src, nA + 16384 + a_dst);
            gload_lds16(wg + sl + 24576 + a_src, nA + 24576 + a_dst);
        }
        PHASE(1)
        PHASE(2)
        PHASE(3)
        if (pre) {
#pragma unroll
            for (int w = 0; w < 2; ++w)
#pragma unroll
                for (int jh = 0; jh < 2; ++jh)
                    *(f16x8*)(nX + xw_base + (w * 2 + jh) * 4096) =
                        cvt2(xr[w * 4 + jh * 2], xr[w * 4 + jh * 2 + 1]);
        }
        __syncthreads();
    }
#undef PHASE

    // ---- epilogue: tanh + W2 dot ----
    // D layout (32x32): col = lane&31, row = (r&3) + 8*(r>>2) + 4*(lane>>5)
    float sp0 = 0.f, sp1 = 0.f;
#pragma unroll
    for (int f = 0; f < 4; ++f) {
#pragma unroll
        for (int rg = 0; rg < 4; ++rg) {
            int mbase = mt * 256 + mg * 128 + f * 32 + rg * 8 + hi * 4;
            float4 w2v = *(const float4*)(W2 + mbase);
            float w2a[4] = {w2v.x, w2v.y, w2v.z, w2v.w};
#pragma unroll
            for (int j = 0; j < 4; ++j) {
                float w2 = w2a[j];
                {
                    float xv = acc[f][0][rg * 4 + j];
                    float e = __expf(2.f * xv);
                    sp0 += w2 * (1.f - 2.f / (e + 1.f));
                }
                {
                    float xv = acc[f][1][rg * 4 + j];
                    float e = __expf(2.f * xv);
                    sp1 += w2 * (1.f - 2.f / (e + 1.f));
                }
            }
        }
    }
    sp0 += __shfl_xor(sp0, 32, 64);   // fold hi halves (same col)
    sp1 += __shfl_xor(sp1, 32, 64);

    float* red = (float*)lds;          // alias buf0 (final reads were buf1)
    if (hi == 0) {
        red[wid * 64 + lr]      = sp0;   // col-local = ng*64 + lr
        red[wid * 64 + 32 + lr] = sp1;   // col-local = ng*64 + 32 + lr
    }
    __syncthreads();
    if (tid < 256) {
        int ngc = tid >> 6;            // ng owning this col
        int cl  = tid & 63;
        float s = red[(0 * 4 + ngc) * 64 + cl] + red[(1 * 4 + ngc) * 64 + cl];
        s_part[(size_t)mt * NCOL + cg * 256 + tid] = s;
    }
}

// ---------------------------------------------------------------------------
// Kernel 2: sum 4 mt-partials, per-l max and sum-exp over B (softmax stats).
// ---------------------------------------------------------------------------
__global__ void k_smax1(const float* __restrict__ s_part,
                        float* __restrict__ s_raw,
                        float* __restrict__ lstats /* [32]: 16 max, 16 sum */) {
    int l = blockIdx.x;
    int t = threadIdx.x;
    int lane = t & 63, wid = t >> 6;

    float v[8];
    float mx = -__builtin_inff();
#pragma unroll
    for (int i = 0; i < 8; ++i) {
        int b = i * 256 + t;
        int id = b * 16 + l;
        float x = s_part[id] + s_part[NCOL + id] +
                  s_part[2 * NCOL + id] + s_part[3 * NCOL + id];
        v[i] = x;
        s_raw[id] = x;
        mx = fmaxf(mx, x);
    }
#pragma unroll
    for (int d = 1; d < 64; d <<= 1) mx = fmaxf(mx, __shfl_xor(mx, d, 64));
    __shared__ float rm[4];
    if (lane == 0) rm[wid] = mx;
    __syncthreads();
    mx = fmaxf(fmaxf(rm[0], rm[1]), fmaxf(rm[2], rm[3]));

    float se = 0.f;
#pragma unroll
    for (int i = 0; i < 8; ++i) se += __expf(v[i] - mx);
#pragma unroll
    for (int d = 1; d < 64; d <<= 1) se += __shfl_xor(se, d, 64);
    __shared__ float rs[4];
    if (lane == 0) rs[wid] = se;
    __syncthreads();
    if (t == 0) {
        lstats[l]      = mx;
        lstats[16 + l] = rs[0] + rs[1] + rs[2] + rs[3];
    }
}

// ---------------------------------------------------------------------------
// Kernel 3: masked softmax over l + weighted gather-sum to output.
// ---------------------------------------------------------------------------
__global__ void k_out(const float* __restrict__ hctx,
                      const int*   __restrict__ offsets,
                      const int*   __restrict__ stc,
                      const int*   __restrict__ sep_l,
                      const float* __restrict__ s_raw,
                      const float* __restrict__ lstats,
                      float* __restrict__ out) {
    int b = blockIdx.x;
    int t = threadIdx.x;

    int off = offsets[b];
    int sep = sep_l[b];
    int st  = stc[b];
    bool in1 = (off <= sep);
    int start = in1 ? imax(off - KW, 0)   : imax(off - KW, sep + 1);
    int end   = in1 ? imin(off + KW, sep) : imin(off + KW, st);

    float p[16];
    float m2 = -__builtin_inff();
#pragma unroll
    for (int l = 0; l < 16; ++l) {
        bool valid = (start + l) < end;
        float s = s_raw[b * 16 + l];
        float pl = __expf(s - lstats[l]) / lstats[16 + l];
        p[l] = valid ? pl : -__builtin_inff();
        m2 = fmaxf(m2, p[l]);
    }
    float q[16];
    float qs = 0.f;
#pragma unroll
    for (int l = 0; l < 16; ++l) {
        float e = __expf(p[l] - m2);   // exp(-inf) = 0 for invalid
        q[l] = e;
        qs += e;
    }
    float rqs = 1.f / qs;

    float4 acc = {0.f, 0.f, 0.f, 0.f};
#pragma unroll
    for (int l = 0; l < 16; ++l) {
        float wl = q[l] * rqs;
        if (wl > 0.f) {
            int tr = imin(imax(start + l, 0), T_DIM - 1);
            float4 x = *((const float4*)(hctx + ((size_t)tr * B_DIM + b) * D_DIM) + t);
            acc.x += wl * x.x; acc.y += wl * x.y;
            acc.z += wl * x.z; acc.w += wl * x.w;
        }
    }
    *((float4*)(out + (size_t)b * D_DIM) + t) = acc;
}

// ---------------------------------------------------------------------------
extern "C" void kernel_launch(void* const* d_in, const int* in_sizes, int n_in,
                              void* d_out, int out_size, void* d_ws, size_t ws_size,
                              hipStream_t stream) {
    const float* hctx    = (const float*)d_in[0];
    const int*   offsets = (const int*)d_in[1];
    const int*   stc     = (const int*)d_in[2];
    const int*   sep     = (const int*)d_in[3];
    // d_in[4] = no_local (unused by reference)
    const float* W1      = (const float*)d_in[5];
    const float* W2      = (const float*)d_in[6];
    float* out = (float*)d_out;

    char* ws = (char*)d_ws;
    _Float16* W1g    = (_Float16*)ws;                              // 2 MB
    float*    s_part = (float*)(ws + (2u << 20));                  // 512 KB
    float*    s_raw  = (float*)(ws + (2u << 20) + (512u << 10));   // 128 KB
    float*    lstats = (float*)(ws + (2u << 20) + (640u << 10));

    hipLaunchKernelGGL(k_cvt_w1, dim3(256),  dim3(256), 0, stream, W1, W1g);
    hipLaunchKernelGGL(k_gemm,   dim3(512),  dim3(512), 0, stream,
                       hctx, offsets, stc, sep, W1g, W2, s_part);
    hipLaunchKernelGGL(k_smax1,  dim3(16),   dim3(256), 0, stream,
                       s_part, s_raw, lstats);
    hipLaunchKernelGGL(k_out,    dim3(2048), dim3(256), 0, stream,
                       hctx, offsets, stc, sep, s_raw, lstats, out);
}

// Round 10
// 598.247 us; speedup vs baseline: 1.0127x; 1.0127x over previous
//
#include <hip/hip_runtime.h>

#define T_DIM 128
#define B_DIM 2048
#define D_DIM 1024
#define KW 8
#define NCOL (B_DIM * 16)      // 32768 columns

// Per double-buffer half: A-tile 32KB [kc<4][jh<2][mloc<256][16B]
//                       + X-tile 32KB [kc<4][jh<2][col<256][16B]
#define BUFB 65536

typedef _Float16 f16x8 __attribute__((ext_vector_type(8)));
typedef float    f32x16 __attribute__((ext_vector_type(16)));

static __device__ __forceinline__ int imax(int a, int b) { return a > b ? a : b; }
static __device__ __forceinline__ int imin(int a, int b) { return a < b ? a : b; }

__device__ __forceinline__ f16x8 cvt2(float4 u, float4 v) {
    f16x8 h;
    h[0] = (_Float16)u.x; h[1] = (_Float16)u.y;
    h[2] = (_Float16)u.z; h[3] = (_Float16)u.w;
    h[4] = (_Float16)v.x; h[5] = (_Float16)v.y;
    h[6] = (_Float16)v.z; h[7] = (_Float16)v.w;
    return h;
}

// ---------------------------------------------------------------------------
// Kernel 0: W1 fp32 [m][k] -> W1g: 64 slabs (ktile<16 x mt<4) of 32KB, each
// the exact linear LDS A-image [kc<4][jh<2][mloc<256][16B]:
//   element = W1[mt*256 + mloc][ktile*64 + kc*16 + jh*8 + j]
// ---------------------------------------------------------------------------
__global__ void k_cvt_w1(const float* __restrict__ W1, _Float16* __restrict__ W1g) {
    int i  = blockIdx.x * 256 + threadIdx.x;   // 65536 threads
    int m  = i >> 6;
    int r  = i & 63;
    int kt = r >> 2;
    int kc = r & 3;
    const float* src = W1 + (size_t)m * D_DIM + kt * 64 + kc * 16;
    float4 x0 = *(const float4*)(src);
    float4 x1 = *(const float4*)(src + 4);
    float4 x2 = *(const float4*)(src + 8);
    float4 x3 = *(const float4*)(src + 12);
    int slab = kt * 4 + (m >> 8);
    int mloc = m & 255;
    _Float16* dst = W1g + (size_t)slab * 16384 + kc * 4096 + mloc * 8;
    *(f16x8*)(dst)        = cvt2(x0, x1);   // jh = 0
    *(f16x8*)(dst + 2048) = cvt2(x2, x3);   // jh = 1
}

// ---------------------------------------------------------------------------
// Kernel 1 (fused gather + 256x256 GEMM + tanh/W2 epilogue):
// grid = 512 blocks (4 mt x 128 cg, XCD-bijective swizzle: mt-siblings of a
// cg share an XCD's L2 for the X stream). 8 waves (mg<2 x ng<4), wave-tile
// 128m x 64n, acc[4][2] of 32x32x16 (128 acc VGPR).
// BOTH operands reg-staged into LDS (no global_load_lds — rounds 6/8/9
// showed a pathology with wid-dependent LDS dest). A: thread copies 16B per
// kc-region (lane-stride-16 ds_write_b128, conflict-free). X: gathered fp32
// -> f16. Staging issued phases 0-1, written phases 2-3, ONE barrier/iter.
// amdgpu_waves_per_eu(2) forces the 256-VGPR budget (launch_bounds 2nd arg
// was ignored: rounds 8/9 both showed VGPR=104 + acc spill => 900us).
// ---------------------------------------------------------------------------
__attribute__((amdgpu_flat_work_group_size(512, 512), amdgpu_waves_per_eu(2)))
__global__ void k_gemm(const float* __restrict__ hctx,
                       const int*   __restrict__ offsets,
                       const int*   __restrict__ stc,
                       const int*   __restrict__ sep_l,
                       const _Float16* __restrict__ W1g,
                       const float* __restrict__ W2,
                       float* __restrict__ s_part /* [4][NCOL] */) {
    __shared__ __align__(16) char lds[2 * BUFB];

    int orig = blockIdx.x;
    int wgid = (orig & 7) * 64 + (orig >> 3);   // bijective: 512 % 8 == 0
    int mt   = wgid & 3;
    int cg   = wgid >> 2;

    int tid  = threadIdx.x;
    int wid  = tid >> 6;
    int lane = tid & 63;
    int lr   = lane & 31;
    int hi   = lane >> 5;
    int mg   = wid >> 2;      // 0..1
    int ng   = wid & 3;       // 0..3

    // ---- X gather setup: thread owns (col, khalf) ----
    int s_col = tid & 255;
    int khalf = tid >> 8;     // 0..1 (k-half of 32 within BK=64)
    int col = cg * 256 + s_col;
    int b   = col >> 4;
    int li  = col & 15;
    int off = offsets[b];
    int sep = sep_l[b];
    int st  = stc[b];
    bool in1 = (off <= sep);
    int start = in1 ? imax(off - KW, 0)   : imax(off - KW, sep + 1);
    int end   = in1 ? imin(off + KW, sep) : imin(off + KW, st);
    int idx = start + li;
    bool valid = (idx < end);
    int tc = imin(imax(idx, 0), T_DIM - 1);
    const float* hrow = hctx + ((size_t)tc * B_DIM + b) * D_DIM + khalf * 32;
    int xw_base = khalf * 16384 + s_col * 16;   // + w*8192 + jh*4096

    // ---- A staging: thread copies 16B of each of the 4 kc-regions ----
    const char* wg = (const char*)W1g;
    int a_t16 = tid * 16;

    // ---- frag read offsets ----
    int a_off = (mg * 128 + lr) * 16;       // + (kc*2+hi)*4096 + f*512
    int x_off = (ng * 64 + lr) * 16;        // + (kc*2+hi)*4096 + nf*512

    f32x16 acc[4][2];
#pragma unroll
    for (int f = 0; f < 4; ++f)
#pragma unroll
        for (int nf = 0; nf < 2; ++nf)
#pragma unroll
            for (int i = 0; i < 16; ++i) acc[f][nf][i] = 0.f;

    float4 z = {0.f, 0.f, 0.f, 0.f};

    // ---- prologue: stage tile 0 into buf0 ----
    {
        const char* sl = wg + (size_t)(0 * 4 + mt) * 32768;
        uint4 ar[4];
#pragma unroll
        for (int q = 0; q < 4; ++q)
            ar[q] = *(const uint4*)(sl + q * 8192 + a_t16);
        float4 xr[8];
#pragma unroll
        for (int i = 0; i < 8; ++i)
            xr[i] = valid ? *(const float4*)(hrow + i * 4) : z;
#pragma unroll
        for (int q = 0; q < 4; ++q)
            *(uint4*)(lds + q * 8192 + a_t16) = ar[q];
#pragma unroll
        for (int w = 0; w < 2; ++w)
#pragma unroll
            for (int jh = 0; jh < 2; ++jh)
                *(f16x8*)(lds + 32768 + xw_base + w * 8192 + jh * 4096) =
                    cvt2(xr[w * 4 + jh * 2], xr[w * 4 + jh * 2 + 1]);
    }
    __syncthreads();

#define PHASE(kc)                                                              \
    {                                                                          \
        const char* pa = bA + ((kc) * 2 + hi) * 4096;                          \
        const char* px = bX + ((kc) * 2 + hi) * 4096;                          \
        f16x8 af0 = *(const f16x8*)(pa + a_off);                               \
        f16x8 af1 = *(const f16x8*)(pa + a_off + 512);                         \
        f16x8 af2 = *(const f16x8*)(pa + a_off + 1024);                        \
        f16x8 af3 = *(const f16x8*)(pa + a_off + 1536);                        \
        f16x8 xf0 = *(const f16x8*)(px + x_off);                               \
        f16x8 xf1 = *(const f16x8*)(px + x_off + 512);                         \
        __builtin_amdgcn_s_setprio(1);                                         \
        acc[0][0] = __builtin_amdgcn_mfma_f32_32x32x16_f16(af0, xf0, acc[0][0], 0, 0, 0); \
        acc[1][0] = __builtin_amdgcn_mfma_f32_32x32x16_f16(af1, xf0, acc[1][0], 0, 0, 0); \
        acc[2][0] = __builtin_amdgcn_mfma_f32_32x32x16_f16(af2, xf0, acc[2][0], 0, 0, 0); \
        acc[3][0] = __builtin_amdgcn_mfma_f32_32x32x16_f16(af3, xf0, acc[3][0], 0, 0, 0); \
        acc[0][1] = __builtin_amdgcn_mfma_f32_32x32x16_f16(af0, xf1, acc[0][1], 0, 0, 0); \
        acc[1][1] = __builtin_amdgcn_mfma_f32_32x32x16_f16(af1, xf1, acc[1][1], 0, 0, 0); \
        acc[2][1] = __builtin_amdgcn_mfma_f32_32x32x16_f16(af2, xf1, acc[2][1], 0, 0, 0); \
        acc[3][1] = __builtin_amdgcn_mfma_f32_32x32x16_f16(af3, xf1, acc[3][1], 0, 0, 0); \
        __builtin_amdgcn_s_setprio(0);                                         \
    }

    // ---- main loop: 16 K-tiles of 64 ----
    for (int t = 0; t < 16; ++t) {
        const char* bA = lds + (t & 1) * BUFB;
        const char* bX = bA + 32768;
        char* nA = lds + ((t & 1) ^ 1) * BUFB;
        char* nX = nA + 32768;
        bool pre = (t < 15);
        const char* sl = wg + (size_t)((t + 1) * 4 + mt) * 32768;
        const float* xsrc = hrow + (t + 1) * 64;

        uint4 ar[4];
        float4 xr[8];
        // phase 0 staging: X loads 0-3, A loads 0-1
        if (pre) {
            xr[0] = valid ? *(const float4*)(xsrc)      : z;
            xr[1] = valid ? *(const float4*)(xsrc + 4)  : z;
            xr[2] = valid ? *(const float4*)(xsrc + 8)  : z;
            xr[3] = valid ? *(const float4*)(xsrc + 12) : z;
            ar[0] = *(const uint4*)(sl + a_t16);
            ar[1] = *(const uint4*)(sl + 8192 + a_t16);
        }
        PHASE(0)
        // phase 1 staging: X loads 4-7, A loads 2-3
        if (pre) {
            xr[4] = valid ? *(const float4*)(xsrc + 16) : z;
            xr[5] = valid ? *(const float4*)(xsrc + 20) : z;
            xr[6] = valid ? *(const float4*)(xsrc + 24) : z;
            xr[7] = valid ? *(const float4*)(xsrc + 28) : z;
            ar[2] = *(const uint4*)(sl + 16384 + a_t16);
            ar[3] = *(const uint4*)(sl + 24576 + a_t16);
        }
        PHASE(1)
        // phase 2 staging: write A 0-1
        if (pre) {
            *(uint4*)(nA + a_t16)        = ar[0];
            *(uint4*)(nA + 8192 + a_t16) = ar[1];
        }
        PHASE(2)
        // phase 3 staging: write A 2-3 + X cvt/write
        if (pre) {
            *(uint4*)(nA + 16384 + a_t16) = ar[2];
            *(uint4*)(nA + 24576 + a_t16) = ar[3];
#pragma unroll
            for (int w = 0; w < 2; ++w)
#pragma unroll
                for (int jh = 0; jh < 2; ++jh)
                    *(f16x8*)(nX + xw_base + w * 8192 + jh * 4096) =
                        cvt2(xr[w * 4 + jh * 2], xr[w * 4 + jh * 2 + 1]);
        }
        PHASE(3)
        __syncthreads();
    }
#undef PHASE

    // ---- epilogue: tanh + W2 dot ----
    // D layout (32x32): col = lane&31, row = (r&3) + 8*(r>>2) + 4*(lane>>5)
    float sp0 = 0.f, sp1 = 0.f;
#pragma unroll
    for (int f = 0; f < 4; ++f) {
#pragma unroll
        for (int rg = 0; rg < 4; ++rg) {
            int mbase = mt * 256 + mg * 128 + f * 32 + rg * 8 + hi * 4;
            float4 w2v = *(const float4*)(W2 + mbase);
            float w2a[4] = {w2v.x, w2v.y, w2v.z, w2v.w};
#pragma unroll
            for (int j = 0; j < 4; ++j) {
                float w2 = w2a[j];
                {
                    float xv = acc[f][0][rg * 4 + j];
                    float e = __expf(2.f * xv);
                    sp0 += w2 * (1.f - 2.f / (e + 1.f));
                }
                {
                    float xv = acc[f][1][rg * 4 + j];
                    float e = __expf(2.f * xv);
                    sp1 += w2 * (1.f - 2.f / (e + 1.f));
                }
            }
        }
    }
    sp0 += __shfl_xor(sp0, 32, 64);   // fold hi halves (same col)
    sp1 += __shfl_xor(sp1, 32, 64);

    float* red = (float*)lds;          // alias buf0 A-region (loop is done)
    if (hi == 0) {
        red[wid * 64 + lr]      = sp0;   // col-local = ng*64 + lr
        red[wid * 64 + 32 + lr] = sp1;   // col-local = ng*64 + 32 + lr
    }
    __syncthreads();
    if (tid < 256) {
        int ngc = tid >> 6;            // ng owning this col
        int cl  = tid & 63;
        float s = red[(0 * 4 + ngc) * 64 + cl] + red[(1 * 4 + ngc) * 64 + cl];
        s_part[(size_t)mt * NCOL + cg * 256 + tid] = s;
    }
}

// ---------------------------------------------------------------------------
// Kernel 2: sum 4 mt-partials, per-l max and sum-exp over B (softmax stats).
// ---------------------------------------------------------------------------
__global__ void k_smax1(const float* __restrict__ s_part,
                        float* __restrict__ s_raw,
                        float* __restrict__ lstats /* [32]: 16 max, 16 sum */) {
    int l = blockIdx.x;
    int t = threadIdx.x;
    int lane = t & 63, wid = t >> 6;

    float v[8];
    float mx = -__builtin_inff();
#pragma unroll
    for (int i = 0; i < 8; ++i) {
        int b = i * 256 + t;
        int id = b * 16 + l;
        float x = s_part[id] + s_part[NCOL + id] +
                  s_part[2 * NCOL + id] + s_part[3 * NCOL + id];
        v[i] = x;
        s_raw[id] = x;
        mx = fmaxf(mx, x);
    }
#pragma unroll
    for (int d = 1; d < 64; d <<= 1) mx = fmaxf(mx, __shfl_xor(mx, d, 64));
    __shared__ float rm[4];
    if (lane == 0) rm[wid] = mx;
    __syncthreads();
    mx = fmaxf(fmaxf(rm[0], rm[1]), fmaxf(rm[2], rm[3]));

    float se = 0.f;
#pragma unroll
    for (int i = 0; i < 8; ++i) se += __expf(v[i] - mx);
#pragma unroll
    for (int d = 1; d < 64; d <<= 1) se += __shfl_xor(se, d, 64);
    __shared__ float rs[4];
    if (lane == 0) rs[wid] = se;
    __syncthreads();
    if (t == 0) {
        lstats[l]      = mx;
        lstats[16 + l] = rs[0] + rs[1] + rs[2] + rs[3];
    }
}

// ---------------------------------------------------------------------------
// Kernel 3: masked softmax over l + weighted gather-sum to output.
// ---------------------------------------------------------------------------
__global__ void k_out(const float* __restrict__ hctx,
                      const int*   __restrict__ offsets,
                      const int*   __restrict__ stc,
                      const int*   __restrict__ sep_l,
                      const float* __restrict__ s_raw,
                      const float* __restrict__ lstats,
                      float* __restrict__ out) {
    int b = blockIdx.x;
    int t = threadIdx.x;

    int off = offsets[b];
    int sep = sep_l[b];
    int st  = stc[b];
    bool in1 = (off <= sep);
    int start = in1 ? imax(off - KW, 0)   : imax(off - KW, sep + 1);
    int end   = in1 ? imin(off + KW, sep) : imin(off + KW, st);

    float p[16];
    float m2 = -__builtin_inff();
#pragma unroll
    for (int l = 0; l < 16; ++l) {
        bool valid = (start + l) < end;
        float s = s_raw[b * 16 + l];
        float pl = __expf(s - lstats[l]) / lstats[16 + l];
        p[l] = valid ? pl : -__builtin_inff();
        m2 = fmaxf(m2, p[l]);
    }
    float q[16];
    float qs = 0.f;
#pragma unroll
    for (int l = 0; l < 16; ++l) {
        float e = __expf(p[l] - m2);   // exp(-inf) = 0 for invalid
        q[l] = e;
        qs += e;
    }
    float rqs = 1.f / qs;

    float4 acc = {0.f, 0.f, 0.f, 0.f};
#pragma unroll
    for (int l = 0; l < 16; ++l) {
        float wl = q[l] * rqs;
        if (wl > 0.f) {
            int tr = imin(imax(start + l, 0), T_DIM - 1);
            float4 x = *((const float4*)(hctx + ((size_t)tr * B_DIM + b) * D_DIM) + t);
            acc.x += wl * x.x; acc.y += wl * x.y;
            acc.z += wl * x.z; acc.w += wl * x.w;
        }
    }
    *((float4*)(out + (size_t)b * D_DIM) + t) = acc;
}

// ---------------------------------------------------------------------------
extern "C" void kernel_launch(void* const* d_in, const int* in_sizes, int n_in,
                              void* d_out, int out_size, void* d_ws, size_t ws_size,
                              hipStream_t stream) {
    const float* hctx    = (const float*)d_in[0];
    const int*   offsets = (const int*)d_in[1];
    const int*   stc     = (const int*)d_in[2];
    const int*   sep     = (const int*)d_in[3];
    // d_in[4] = no_local (unused by reference)
    const float* W1      = (const float*)d_in[5];
    const float* W2      = (const float*)d_in[6];
    float* out = (float*)d_out;

    char* ws = (char*)d_ws;
    _Float16* W1g    = (_Float16*)ws;                              // 2 MB
    float*    s_part = (float*)(ws + (2u << 20));                  // 512 KB
    float*    s_raw  = (float*)(ws + (2u << 20) + (512u << 10));   // 128 KB
    float*    lstats = (float*)(ws + (2u << 20) + (640u << 10));

    hipLaunchKernelGGL(k_cvt_w1, dim3(256),  dim3(256), 0, stream, W1, W1g);
    hipLaunchKernelGGL(k_gemm,   dim3(512),  dim3(512), 0, stream,
                       hctx, offsets, stc, sep, W1g, W2, s_part);
    hipLaunchKernelGGL(k_smax1,  dim3(16),   dim3(256), 0, stream,
                       s_part, s_raw, lstats);
    hipLaunchKernelGGL(k_out,    dim3(2048), dim3(256), 0, stream,
                       hctx, offsets, stc, sep, s_raw, lstats, out);
}

// Round 11
// 217.243 us; speedup vs baseline: 2.7889x; 2.7538x over previous
//
#include <hip/hip_runtime.h>

#define T_DIM 128
#define B_DIM 2048
#define D_DIM 1024
#define KW 8
#define NCOL (B_DIM * 16)      // 32768 columns

// X LDS tile per buffer: [kc<4][jh<2][col<64][8 f16], plane padded +16B.
#define PL   2064              // 2*64*16 + 16
#define BUFB (4 * PL)          // 8256 B per buffer
#define CHUNKS 16              // K chunks of 64

typedef _Float16 f16x8 __attribute__((ext_vector_type(8)));
typedef float    f32x16 __attribute__((ext_vector_type(16)));

static __device__ __forceinline__ int imax(int a, int b) { return a > b ? a : b; }
static __device__ __forceinline__ int imin(int a, int b) { return a < b ? a : b; }

__device__ __forceinline__ f16x8 cvt2(float4 u, float4 v) {
    f16x8 h;
    h[0] = (_Float16)u.x; h[1] = (_Float16)u.y;
    h[2] = (_Float16)u.z; h[3] = (_Float16)u.w;
    h[4] = (_Float16)v.x; h[5] = (_Float16)v.y;
    h[6] = (_Float16)v.z; h[7] = (_Float16)v.w;
    return h;
}

// ---------------------------------------------------------------------------
// Kernel 0: W1 fp32 [m][k] -> fp16 fragment-interleaved W1f[kc][m][j]
//   W1f[(kc*1024 + m)*16 + j] = W1[m*1024 + kc*16 + j],  kc<64, j<16
// (identical to the round-4/5 version that measured fine)
// ---------------------------------------------------------------------------
__global__ void k_cvt_w1(const float* __restrict__ W1, _Float16* __restrict__ W1f) {
    int i  = blockIdx.x * 256 + threadIdx.x;   // 65536 threads
    int m  = i >> 6;
    int kc = i & 63;
    const float* src = W1 + (size_t)m * D_DIM + kc * 16;
    float4 x0 = *(const float4*)(src);
    float4 x1 = *(const float4*)(src + 4);
    float4 x2 = *(const float4*)(src + 8);
    float4 x3 = *(const float4*)(src + 12);
    _Float16* dst = W1f + ((size_t)kc * 1024 + m) * 16;
    *(f16x8*)(dst)     = cvt2(x0, x1);
    *(f16x8*)(dst + 8) = cvt2(x2, x3);
}

// ---------------------------------------------------------------------------
// Kernel 1 (fused gather + GEMM + tanh/W2 epilogue) — round-5 schedule with
// 256-thread blocks for 2-blocks/CU co-residency (barrier-stall hiding).
// Block: 512 m (mt half of W1) x 64 cols; 4 waves, wave-tile 128m x 64n,
// acc[4][2] of 32x32x16. A streamed from L2-resident W1f with depth-2
// register prefetch; X gathered fp32->f16 staged in LDS (dbuf, BK=64,
// 4 float4 in flight per thread), depth-1 LDS prefetch for X frags.
// grid = 1024: bid -> mt = bid&1 (m half, twins share X stream via L2),
// cg = bid>>1. Writes s_part[mt][col] = partial over 512 m.
// ---------------------------------------------------------------------------
__launch_bounds__(256, 2)
__global__ void k_gemm(const float* __restrict__ hctx,
                       const int*   __restrict__ offsets,
                       const int*   __restrict__ stc,
                       const int*   __restrict__ sep_l,
                       const _Float16* __restrict__ W1f,
                       const float* __restrict__ W2,
                       float* __restrict__ s_part /* [2][NCOL] */) {
    __shared__ __align__(16) char ldsx[2 * BUFB];
    __shared__ float red[4][64];

    int bid  = blockIdx.x;
    int mt   = bid & 1;
    int cg   = bid >> 1;
    int tid  = threadIdx.x;
    int wid  = tid >> 6;        // 0..3
    int lane = tid & 63;
    int lr   = lane & 31;
    int hi   = lane >> 5;

    // ---- X staging geometry: thread owns (col, kc-slot) ----
    int sc  = tid & 63;         // col within group
    int kcs = tid >> 6;         // 0..3: which kc-plane of the chunk
    int col = cg * 64 + sc;
    int b   = col >> 4;
    int li  = col & 15;
    int off = offsets[b];
    int sep = sep_l[b];
    int st  = stc[b];
    bool in1 = (off <= sep);
    int start = in1 ? imax(off - KW, 0)   : imax(off - KW, sep + 1);
    int end   = in1 ? imin(off + KW, sep) : imin(off + KW, st);
    int idx = start + li;
    bool valid = (idx < end);
    int tc = imin(imax(idx, 0), T_DIM - 1);
    const float* sbase = hctx + ((size_t)tc * B_DIM + b) * D_DIM + kcs * 16;
    int wr0 = kcs * PL + sc * 16;          // jh=0 write; jh=1 at +1024

    // ---- A geometry: frag (f, kc) at ap + kc*16384 + f*512 ----
    const _Float16* ap = W1f + (size_t)(mt * 512 + wid * 128 + lr) * 16 + hi * 8;
    int rd_off = hi * 1024 + lr * 16;      // + kc*PL (+512 for col-frag 1)

    f32x16 acc[4][2];
#pragma unroll
    for (int f = 0; f < 4; ++f)
#pragma unroll
        for (int nf = 0; nf < 2; ++nf)
#pragma unroll
            for (int i = 0; i < 16; ++i) acc[f][nf][i] = 0.f;

    float4 z = {0.f, 0.f, 0.f, 0.f};

    // ---- prologue: stage chunk 0 into buf0 ----
    {
        float4 x0 = valid ? *(const float4*)(sbase)      : z;
        float4 x1 = valid ? *(const float4*)(sbase + 4)  : z;
        float4 x2 = valid ? *(const float4*)(sbase + 8)  : z;
        float4 x3 = valid ? *(const float4*)(sbase + 12) : z;
        *(f16x8*)(ldsx + wr0)        = cvt2(x0, x1);
        *(f16x8*)(ldsx + wr0 + 1024) = cvt2(x2, x3);
    }

    // A pipeline: a0 = a(0), a1 = a(1)
    f16x8 a0[4], a1[4];
#pragma unroll
    for (int f = 0; f < 4; ++f) a0[f] = *(const f16x8*)(ap + f * 512);
#pragma unroll
    for (int f = 0; f < 4; ++f) a1[f] = *(const f16x8*)(ap + 16384 + f * 512);

    __syncthreads();

    // B pipeline: b0 = frags of kc-plane 0, buf0
    f16x8 b0[2];
    b0[0] = *(const f16x8*)(ldsx + rd_off);
    b0[1] = *(const f16x8*)(ldsx + rd_off + 512);

    // ---- main loop: 16 chunks of 64 k (4 kc of 16) ----
    for (int c = 0; c < CHUNKS; ++c) {
        int bufr = (c & 1) * BUFB;

        // T14: issue next chunk's global X loads before compute
        float4 xn0, xn1, xn2, xn3;
        if (c < CHUNKS - 1) {
            const float* sp = sbase + (c + 1) * 64;
            xn0 = valid ? *(const float4*)(sp)      : z;
            xn1 = valid ? *(const float4*)(sp + 4)  : z;
            xn2 = valid ? *(const float4*)(sp + 8)  : z;
            xn3 = valid ? *(const float4*)(sp + 12) : z;
        }

#pragma unroll
        for (int kcL = 0; kcL < 4; ++kcL) {
            int kc = c * 4 + kcL;
            int ka = (kc + 2) & 63;          // depth-2 A prefetch

            f16x8 a2[4];
#pragma unroll
            for (int f = 0; f < 4; ++f)
                a2[f] = *(const f16x8*)(ap + (size_t)ka * 16384 + f * 512);

            f16x8 b1[2];
            if (kcL < 3) {                    // depth-1 B prefetch (same buf)
                const char* bp = ldsx + bufr + (kcL + 1) * PL + rd_off;
                b1[0] = *(const f16x8*)(bp);
                b1[1] = *(const f16x8*)(bp + 512);
            }

#pragma unroll
            for (int f = 0; f < 4; ++f)
                acc[f][0] = __builtin_amdgcn_mfma_f32_32x32x16_f16(
                    a0[f], b0[0], acc[f][0], 0, 0, 0);
#pragma unroll
            for (int f = 0; f < 4; ++f)
                acc[f][1] = __builtin_amdgcn_mfma_f32_32x32x16_f16(
                    a0[f], b0[1], acc[f][1], 0, 0, 0);

#pragma unroll
            for (int f = 0; f < 4; ++f) { a0[f] = a1[f]; a1[f] = a2[f]; }
            if (kcL < 3) { b0[0] = b1[0]; b0[1] = b1[1]; }
        }

        // write staged chunk into the other buffer
        if (c < CHUNKS - 1) {
            int bufw = ((c + 1) & 1) * BUFB;
            *(f16x8*)(ldsx + bufw + wr0)        = cvt2(xn0, xn1);
            *(f16x8*)(ldsx + bufw + wr0 + 1024) = cvt2(xn2, xn3);
        }
        __syncthreads();
        if (c < CHUNKS - 1) {    // refill b0 from the fresh buffer (kc-plane 0)
            const char* bp = ldsx + ((c + 1) & 1) * BUFB + rd_off;
            b0[0] = *(const f16x8*)(bp);
            b0[1] = *(const f16x8*)(bp + 512);
        }
    }

    // ---- epilogue: tanh + W2 dot ----
    // D layout (32x32): col = lane&31, row = (r&3) + 8*(r>>2) + 4*(lane>>5)
    int m_wg = mt * 512 + wid * 128;
    float sp0 = 0.f, sp1 = 0.f;
#pragma unroll
    for (int f = 0; f < 4; ++f) {
#pragma unroll
        for (int rg = 0; rg < 4; ++rg) {
            int mbase = m_wg + f * 32 + rg * 8 + hi * 4;
            float4 w2v = *(const float4*)(W2 + mbase);
            float w2a[4] = {w2v.x, w2v.y, w2v.z, w2v.w};
#pragma unroll
            for (int j = 0; j < 4; ++j) {
                float w2 = w2a[j];
                {
                    float x = acc[f][0][rg * 4 + j];
                    float e = __expf(2.f * x);
                    sp0 += w2 * (1.f - 2.f / (e + 1.f));
                }
                {
                    float x = acc[f][1][rg * 4 + j];
                    float e = __expf(2.f * x);
                    sp1 += w2 * (1.f - 2.f / (e + 1.f));
                }
            }
        }
    }
    sp0 += __shfl_xor(sp0, 32, 64);
    sp1 += __shfl_xor(sp1, 32, 64);

    if (hi == 0) {
        red[wid][lr]      = sp0;
        red[wid][32 + lr] = sp1;
    }
    __syncthreads();
    if (tid < 64) {
        float s = red[0][tid] + red[1][tid] + red[2][tid] + red[3][tid];
        s_part[(size_t)mt * NCOL + cg * 64 + tid] = s;
    }
}

// ---------------------------------------------------------------------------
// Kernel 2: sum mt-partials, per-l max and sum-exp over B (softmax stats).
// ---------------------------------------------------------------------------
__global__ void k_smax1(const float* __restrict__ s_part,
                        float* __restrict__ s_raw,
                        float* __restrict__ lstats /* [32]: 16 max, 16 sum */) {
    int l = blockIdx.x;
    int t = threadIdx.x;
    int lane = t & 63, wid = t >> 6;

    float v[8];
    float mx = -__builtin_inff();
#pragma unroll
    for (int i = 0; i < 8; ++i) {
        int b = i * 256 + t;
        int id = b * 16 + l;
        float x = s_part[id] + s_part[NCOL + id];
        v[i] = x;
        s_raw[id] = x;
        mx = fmaxf(mx, x);
    }
#pragma unroll
    for (int d = 1; d < 64; d <<= 1) mx = fmaxf(mx, __shfl_xor(mx, d, 64));
    __shared__ float rm[4];
    if (lane == 0) rm[wid] = mx;
    __syncthreads();
    mx = fmaxf(fmaxf(rm[0], rm[1]), fmaxf(rm[2], rm[3]));

    float se = 0.f;
#pragma unroll
    for (int i = 0; i < 8; ++i) se += __expf(v[i] - mx);
#pragma unroll
    for (int d = 1; d < 64; d <<= 1) se += __shfl_xor(se, d, 64);
    __shared__ float rs[4];
    if (lane == 0) rs[wid] = se;
    __syncthreads();
    if (t == 0) {
        lstats[l]      = mx;
        lstats[16 + l] = rs[0] + rs[1] + rs[2] + rs[3];
    }
}

// ---------------------------------------------------------------------------
// Kernel 3: masked softmax over l + weighted gather-sum to output.
// ---------------------------------------------------------------------------
__global__ void k_out(const float* __restrict__ hctx,
                      const int*   __restrict__ offsets,
                      const int*   __restrict__ stc,
                      const int*   __restrict__ sep_l,
                      const float* __restrict__ s_raw,
                      const float* __restrict__ lstats,
                      float* __restrict__ out) {
    int b = blockIdx.x;
    int t = threadIdx.x;

    int off = offsets[b];
    int sep = sep_l[b];
    int st  = stc[b];
    bool in1 = (off <= sep);
    int start = in1 ? imax(off - KW, 0)   : imax(off - KW, sep + 1);
    int end   = in1 ? imin(off + KW, sep) : imin(off + KW, st);

    float p[16];
    float m2 = -__builtin_inff();
#pragma unroll
    for (int l = 0; l < 16; ++l) {
        bool valid = (start + l) < end;
        float s = s_raw[b * 16 + l];
        float pl = __expf(s - lstats[l]) / lstats[16 + l];
        p[l] = valid ? pl : -__builtin_inff();
        m2 = fmaxf(m2, p[l]);
    }
    float q[16];
    float qs = 0.f;
#pragma unroll
    for (int l = 0; l < 16; ++l) {
        float e = __expf(p[l] - m2);   // exp(-inf) = 0 for invalid
        q[l] = e;
        qs += e;
    }
    float rqs = 1.f / qs;

    float4 acc = {0.f, 0.f, 0.f, 0.f};
#pragma unroll
    for (int l = 0; l < 16; ++l) {
        float wl = q[l] * rqs;
        if (wl > 0.f) {
            int tr = imin(imax(start + l, 0), T_DIM - 1);
            float4 x = *((const float4*)(hctx + ((size_t)tr * B_DIM + b) * D_DIM) + t);
            acc.x += wl * x.x; acc.y += wl * x.y;
            acc.z += wl * x.z; acc.w += wl * x.w;
        }
    }
    *((float4*)(out + (size_t)b * D_DIM) + t) = acc;
}

// ---------------------------------------------------------------------------
extern "C" void kernel_launch(void* const* d_in, const int* in_sizes, int n_in,
                              void* d_out, int out_size, void* d_ws, size_t ws_size,
                              hipStream_t stream) {
    const float* hctx    = (const float*)d_in[0];
    const int*   offsets = (const int*)d_in[1];
    const int*   stc     = (const int*)d_in[2];
    const int*   sep     = (const int*)d_in[3];
    // d_in[4] = no_local (unused by reference)
    const float* W1      = (const float*)d_in[5];
    const float* W2      = (const float*)d_in[6];
    float* out = (float*)d_out;

    char* ws = (char*)d_ws;
    _Float16* W1f    = (_Float16*)ws;                              // 2 MB
    float*    s_part = (float*)(ws + (2u << 20));                  // 256 KB
    float*    s_raw  = (float*)(ws + (2u << 20) + (256u << 10));   // 128 KB
    float*    lstats = (float*)(ws + (2u << 20) + (384u << 10));

    hipLaunchKernelGGL(k_cvt_w1, dim3(256),  dim3(256), 0, stream, W1, W1f);
    hipLaunchKernelGGL(k_gemm,   dim3(1024), dim3(256), 0, stream,
                       hctx, offsets, stc, sep, W1f, W2, s_part);
    hipLaunchKernelGGL(k_smax1,  dim3(16),   dim3(256), 0, stream,
                       s_part, s_raw, lstats);
    hipLaunchKernelGGL(k_out,    dim3(2048), dim3(256), 0, stream,
                       hctx, offsets, stc, sep, s_raw, lstats, out);
}